// Round 3
// baseline (234.059 us; speedup 1.0000x reference)
//
#include <hip/hip_runtime.h>

#define BATCH 2
#define C 512
#define C2 256
#define V 4096          // 16*16*16
#define NROWS 8192      // BATCH*V
#define EPS 1e-5f
#define SLOPE 0.01f
#define LDSW 72         // LDS row stride in bf16 (144B) -> conflict-free frags

typedef __bf16 bf16;
typedef __bf16 bf16x8 __attribute__((ext_vector_type(8)));
typedef __bf16 bf16x4 __attribute__((ext_vector_type(4)));
typedef float  f32x4  __attribute__((ext_vector_type(4)));

__device__ __forceinline__ float leaky(float x) { return x >= 0.f ? x : SLOPE * x; }

// neighbor voxel (within batch) for shift k: 0:d-1 1:d+1 2:w-1 3:w+1 4:h-1 5:h+1 (cyclic)
__device__ __forceinline__ int nbr(int v, int k) {
    int h = v & 15, w = (v >> 4) & 15, d = v >> 8;
    switch (k) {
        case 0: return (v & 0x0FF) | (((d + 15) & 15) << 8);
        case 1: return (v & 0x0FF) | (((d + 1) & 15) << 8);
        case 2: return (v & 0xF0F) | (((w + 15) & 15) << 4);
        case 3: return (v & 0xF0F) | (((w + 1) & 15) << 4);
        case 4: return (v & 0xFF0) | ((h + 15) & 15);
        default: return (v & 0xFF0) | ((h + 1) & 15);
    }
}

struct Stage { uint4 r[4]; };

// load 64B (4 x b128) for this thread's (row, col) slice
__device__ __forceinline__ void issue_rows(Stage& s, const bf16* __restrict__ src,
                                           int ld, int row, int col)
{
    const bf16* p = src + (size_t)row * ld + col;
    s.r[0] = *(const uint4*)(p);
    s.r[1] = *(const uint4*)(p + 8);
    s.r[2] = *(const uint4*)(p + 16);
    s.r[3] = *(const uint4*)(p + 24);
}

__device__ __forceinline__ void commit(bf16* lds, const Stage& s, int t)
{
    bf16* p = lds + (t >> 1) * LDSW + (t & 1) * 32;
    *(uint4*)(p)      = s.r[0];
    *(uint4*)(p + 8)  = s.r[1];
    *(uint4*)(p + 16) = s.r[2];
    *(uint4*)(p + 24) = s.r[3];
}

// edge feature: e = xa*xn + tp (computed at commit time, after vmcnt waits)
__device__ __forceinline__ void commit_edge(bf16* lds, const Stage& a, const Stage& b,
                                            float tp, int t)
{
    bf16* p = lds + (t >> 1) * LDSW + (t & 1) * 32;
    #pragma unroll
    for (int j = 0; j < 4; j++) {
        bf16x8 xa = *(const bf16x8*)&a.r[j];
        bf16x8 xn = *(const bf16x8*)&b.r[j];
        bf16x8 e;
        #pragma unroll
        for (int i = 0; i < 8; i++)
            e[i] = (bf16)fmaf((float)xa[i], (float)xn[i], tp);
        *(bf16x8*)(p + j * 8) = e;
    }
}

// one BK=64 step: wave-tile 64M x 32N, 16 MFMA, 12 ds_read_b128
__device__ __forceinline__ void mm64(const bf16* A, const bf16* B,
                                     f32x4 (&acc)[4][2], int lr, int kg, int bbase)
{
    #pragma unroll
    for (int s = 0; s < 2; s++) {
        const int col = s * 32 + kg * 8;
        bf16x8 af[4], bv[2];
        #pragma unroll
        for (int mb = 0; mb < 4; mb++)
            af[mb] = *(const bf16x8*)(A + (mb * 16 + lr) * LDSW + col);
        #pragma unroll
        for (int nb = 0; nb < 2; nb++)
            bv[nb] = *(const bf16x8*)(B + (bbase + nb * 16 + lr) * LDSW + col);
        #pragma unroll
        for (int mb = 0; mb < 4; mb++)
            #pragma unroll
            for (int nb = 0; nb < 2; nb++)
                acc[mb][nb] = __builtin_amdgcn_mfma_f32_16x16x32_bf16(af[mb], bv[nb], acc[mb][nb], 0, 0, 0);
    }
}

// ---------------------------------------------------------------------------
// prep: fold BN into weights (bf16) + biases/scalars (fp32)
// ---------------------------------------------------------------------------
__global__ __launch_bounds__(256) void k_prep(
    const float* wv, const float* we, const float* wf,
    const float* w_ea, const float* b_ea, const float* g_ea, const float* be_ea,
    const float* rm_ea, const float* rv_ea,
    const float* b_v, const float* g_v, const float* be_v, const float* rm_v, const float* rv_v,
    const float* b_e, const float* g_e, const float* be_e, const float* rm_e, const float* rv_e,
    const float* w_r, const float* b_r, const float* g_r, const float* be_r,
    const float* rm_r, const float* rv_r,
    const float* g_f, const float* be_f, const float* rm_f, const float* rv_f,
    float* P, float* obv, float* obe, float* obf,
    bf16* owv, bf16* owe, bf16* owf)
{
    int i = blockIdx.x * 256 + threadIdx.x;
    if (i < 262144) {
        int o = i >> 10;
        owv[i] = (bf16)(rsqrtf(rv_v[o] + EPS) * g_v[o] * wv[i]);
    } else if (i < 524288) {
        int j = i - 262144; int o = j >> 10;
        owe[j] = (bf16)(rsqrtf(rv_e[o] + EPS) * g_e[o] * we[j]);
    } else if (i < 917504) {
        int j = i - 524288; int o = j / 768;
        owf[j] = (bf16)(rsqrtf(rv_f[o] + EPS) * g_f[o] * wf[j]);
    }
    if (blockIdx.x == 0) {
        int t = threadIdx.x;
        obf[t]       = be_f[t]       - rsqrtf(rv_f[t]       + EPS) * g_f[t]       * rm_f[t];
        obf[t + 256] = be_f[t + 256] - rsqrtf(rv_f[t + 256] + EPS) * g_f[t + 256] * rm_f[t + 256];
        float sv = rsqrtf(rv_v[t] + EPS) * g_v[t];
        obv[t] = sv * (b_v[t] - rm_v[t]) + be_v[t];
        float se = rsqrtf(rv_e[t] + EPS) * g_e[t];
        obe[t] = se * (b_e[t] - rm_e[t]) + be_e[t];
        if (t < 6) {
            float sa = rsqrtf(rv_ea[0] + EPS) * g_ea[0];
            P[t] = sa * w_ea[t];
            float sr = rsqrtf(rv_r[0] + EPS) * g_r[0];
            P[8 + t] = sr * w_r[t];
        }
        if (t == 6) {
            float sa = rsqrtf(rv_ea[0] + EPS) * g_ea[0];
            P[6] = sa * (b_ea[0] - rm_ea[0]) + be_ea[0];
            float sr = rsqrtf(rv_r[0] + EPS) * g_r[0];
            P[14] = sr * (b_r[0] - rm_r[0]) + be_r[0];
        }
    }
}

// ---------------------------------------------------------------------------
// k_aggT: per (b, 64c x 64v) tile, compute agg; write xT/aggT transposed
// [b*V+v][c] bf16 via LDS.
// ---------------------------------------------------------------------------
__global__ __launch_bounds__(256) void k_aggT(
    const float* __restrict__ x, const float* __restrict__ topo,
    const float* __restrict__ P,
    bf16* __restrict__ xT, bf16* __restrict__ aggT)
{
    __shared__ float T[64][65];
    const int t = threadIdx.x;
    const int b = blockIdx.z, ct = blockIdx.y * 64, vt = blockIdx.x * 64;
    const int cl = t >> 2;
    const int c  = ct + cl;
    const int vl0 = (t & 3) * 16;
    const int v0 = vt + vl0;
    const int w = (v0 >> 4) & 15, d = v0 >> 8;
    const float* xp = x + (((size_t)b * C + c) << 12);

    float xr[16], xd0[16], xd1[16], xw0[16], xw1[16];
    #pragma unroll
    for (int i = 0; i < 4; i++) {
        float4 a;
        a = ((const float4*)(xp + v0))[i];                        xr [4*i]=a.x; xr [4*i+1]=a.y; xr [4*i+2]=a.z; xr [4*i+3]=a.w;
        a = ((const float4*)(xp + (((d+15)&15)<<8) + (w<<4)))[i]; xd0[4*i]=a.x; xd0[4*i+1]=a.y; xd0[4*i+2]=a.z; xd0[4*i+3]=a.w;
        a = ((const float4*)(xp + (((d+ 1)&15)<<8) + (w<<4)))[i]; xd1[4*i]=a.x; xd1[4*i+1]=a.y; xd1[4*i+2]=a.z; xd1[4*i+3]=a.w;
        a = ((const float4*)(xp + (d<<8) + (((w+15)&15)<<4)))[i]; xw0[4*i]=a.x; xw0[4*i+1]=a.y; xw0[4*i+2]=a.z; xw0[4*i+3]=a.w;
        a = ((const float4*)(xp + (d<<8) + (((w+ 1)&15)<<4)))[i]; xw1[4*i]=a.x; xw1[4*i+1]=a.y; xw1[4*i+2]=a.z; xw1[4*i+3]=a.w;
    }

    #pragma unroll
    for (int p = 0; p < 2; ++p) {
        float val[16];
        if (p == 0) {
            #pragma unroll
            for (int j = 0; j < 16; j++) val[j] = xr[j];
        } else {
            #pragma unroll
            for (int j = 0; j < 16; j++) {
                const float* tp = topo + (size_t)(v0 + j) * 6;
                float s = P[6];
                s = fmaf(P[0], fmaf(xd0[j], xr[j], tp[0]), s);
                s = fmaf(P[1], fmaf(xd1[j], xr[j], tp[1]), s);
                s = fmaf(P[2], fmaf(xw0[j], xr[j], tp[2]), s);
                s = fmaf(P[3], fmaf(xw1[j], xr[j], tp[3]), s);
                s = fmaf(P[4], fmaf(xr[(j+15)&15], xr[j], tp[4]), s);
                s = fmaf(P[5], fmaf(xr[(j+ 1)&15], xr[j], tp[5]), s);
                val[j] = leaky(s);
            }
        }
        __syncthreads();
        #pragma unroll
        for (int j = 0; j < 16; j++) T[cl][vl0 + j] = val[j];
        __syncthreads();
        const int vr = t >> 2, c0 = (t & 3) * 16;
        bf16x8 lo, hi;
        #pragma unroll
        for (int i = 0; i < 8; i++) {
            lo[i] = (bf16)T[c0 + i][vr];
            hi[i] = (bf16)T[c0 + 8 + i][vr];
        }
        bf16* dst = (p == 0) ? xT : aggT;
        bf16* dp = dst + ((size_t)(b << 12) + vt + vr) * C + ct + c0;
        *(bf16x8*)dp = lo;
        *(bf16x8*)(dp + 8) = hi;
    }
}

// ---------------------------------------------------------------------------
// k_uv: uvT[row][o] = leaky(Wv'.[xT;aggT] + bv').  M=256, N=8192, K=1024.
// Tile 64x64, BK=64, 128 thr (2 waves), double-buffered pipeline.
// ---------------------------------------------------------------------------
__global__ __launch_bounds__(128, 2) void k_uv(
    const bf16* __restrict__ xT, const bf16* __restrict__ aggT,
    const bf16* __restrict__ wv, const float* __restrict__ bv,
    bf16* __restrict__ uvT)
{
    __shared__ __align__(16) bf16 L[2][2][64 * LDSW];
    const int t = threadIdx.x, lane = t & 63, wn = t >> 6;
    const int lr = lane & 15, kg = lane >> 4;
    const int n0 = blockIdx.x * 64, m0 = blockIdx.y * 64;
    const int srow = t >> 1, scolh = (t & 1) * 32;

    f32x4 acc[4][2];
    #pragma unroll
    for (int mb = 0; mb < 4; mb++)
        #pragma unroll
        for (int nb = 0; nb < 2; nb++) acc[mb][nb] = 0.f;

    Stage sA, sB;
    auto issueStep = [&](int s) {
        issue_rows(sA, wv, 1024, m0 + srow, s * 64 + scolh);
        const bf16* bs = (s < 8) ? xT : aggT;
        issue_rows(sB, bs, C, n0 + srow, (s & 7) * 64 + scolh);
    };

    issueStep(0);
    commit(L[0][0], sA, t);
    commit(L[0][1], sB, t);
    int cb = 0;
    #pragma unroll 1
    for (int s = 0; s < 16; ++s) {
        __syncthreads();
        if (s + 1 < 16) issueStep(s + 1);
        mm64(L[cb][0], L[cb][1], acc, lr, kg, wn * 32);
        __syncthreads();
        if (s + 1 < 16) { commit(L[cb ^ 1][0], sA, t); commit(L[cb ^ 1][1], sB, t); }
        cb ^= 1;
    }

    f32x4 bvv[4];
    #pragma unroll
    for (int mb = 0; mb < 4; mb++)
        bvv[mb] = *(const f32x4*)(bv + m0 + mb * 16 + kg * 4);
    #pragma unroll
    for (int mb = 0; mb < 4; mb++)
        #pragma unroll
        for (int nb = 0; nb < 2; nb++) {
            const int col = n0 + wn * 32 + nb * 16 + lr;
            const int o = m0 + mb * 16 + kg * 4;
            bf16x4 o4;
            #pragma unroll
            for (int q = 0; q < 4; q++)
                o4[q] = (bf16)leaky(acc[mb][nb][q] + bvv[mb][q]);
            *(bf16x4*)(uvT + (size_t)col * C2 + o) = o4;
        }
}

// ---------------------------------------------------------------------------
// k_upd: sxe (8 steps) + 6 edge phases (8 steps each, edge built on the fly)
// + ur reduction; epilogue updT = uvT * leaky(ur + br').  M=256, N=8192.
// ---------------------------------------------------------------------------
__global__ __launch_bounds__(128, 2) void k_upd(
    const bf16* __restrict__ xT, const bf16* __restrict__ we,
    const float* __restrict__ bep, const float* __restrict__ P,
    const float* __restrict__ topo, const bf16* __restrict__ uvT,
    bf16* __restrict__ updT)
{
    __shared__ __align__(16) bf16 L[2][2][64 * LDSW];
    const int t = threadIdx.x, lane = t & 63, wn = t >> 6;
    const int lr = lane & 15, kg = lane >> 4;
    const int n0 = blockIdx.x * 64, m0 = blockIdx.y * 64;
    const int srow = t >> 1, scolh = (t & 1) * 32;
    const int nrow = n0 + srow, bb = nrow >> 12, vv = nrow & 4095;

    f32x4 sxe[4][2], ur[4][2], cur[4][2];
    #pragma unroll
    for (int mb = 0; mb < 4; mb++)
        #pragma unroll
        for (int nb = 0; nb < 2; nb++) { sxe[mb][nb] = 0.f; ur[mb][nb] = 0.f; cur[mb][nb] = 0.f; }

    f32x4 bev[4];
    #pragma unroll
    for (int mb = 0; mb < 4; mb++)
        bev[mb] = *(const f32x4*)(bep + m0 + mb * 16 + kg * 4);

    Stage sA, sB, sBn;
    float tp = 0.f;
    auto issueStep = [&](int s) {
        if (s < 8) {
            issue_rows(sA, we, 1024, m0 + srow, s * 64 + scolh);
            issue_rows(sB, xT, C, nrow, s * 64 + scolh);
        } else {
            const int k = (s - 8) >> 3, kc = ((s - 8) & 7) * 64;
            issue_rows(sA, we, 1024, m0 + srow, 512 + kc + scolh);
            issue_rows(sB, xT, C, nrow, kc + scolh);
            const int nv = (bb << 12) | nbr(vv, k);
            issue_rows(sBn, xT, C, nv, kc + scolh);
            tp = topo[vv * 6 + k];
        }
    };
    auto commitStep = [&](int buf, int s) {
        commit(L[buf][0], sA, t);
        if (s < 8) commit(L[buf][1], sB, t);
        else       commit_edge(L[buf][1], sB, sBn, tp, t);
    };

    issueStep(0);
    commitStep(0, 0);
    int cb = 0;
    #pragma unroll 1
    for (int s = 0; s < 56; ++s) {
        __syncthreads();
        if (s + 1 < 56) issueStep(s + 1);
        if (s < 8) mm64(L[cb][0], L[cb][1], sxe, lr, kg, wn * 32);
        else       mm64(L[cb][0], L[cb][1], cur, lr, kg, wn * 32);
        __syncthreads();
        if (s + 1 < 56) commitStep(cb ^ 1, s + 1);
        if (s == 7) {
            #pragma unroll
            for (int mb = 0; mb < 4; mb++)
                #pragma unroll
                for (int nb = 0; nb < 2; nb++) cur[mb][nb] = sxe[mb][nb];
        } else if (s >= 8 && ((s - 8) & 7) == 7) {
            const int k = (s - 8) >> 3;
            const float wrk = P[8 + k];
            #pragma unroll
            for (int mb = 0; mb < 4; mb++)
                #pragma unroll
                for (int nb = 0; nb < 2; nb++)
                    #pragma unroll
                    for (int q = 0; q < 4; q++) {
                        float ue = leaky(cur[mb][nb][q] + bev[mb][q]);
                        ur[mb][nb][q] = fmaf(wrk, ue, ur[mb][nb][q]);
                    }
            if (s < 55) {
                #pragma unroll
                for (int mb = 0; mb < 4; mb++)
                    #pragma unroll
                    for (int nb = 0; nb < 2; nb++) cur[mb][nb] = sxe[mb][nb];
            }
        }
        cb ^= 1;
    }

    const float brp = P[14];
    #pragma unroll
    for (int mb = 0; mb < 4; mb++)
        #pragma unroll
        for (int nb = 0; nb < 2; nb++) {
            const int col = n0 + wn * 32 + nb * 16 + lr;
            const int o = m0 + mb * 16 + kg * 4;
            bf16x4 uv4 = *(const bf16x4*)(uvT + (size_t)col * C2 + o);
            bf16x4 o4;
            #pragma unroll
            for (int q = 0; q < 4; q++) {
                float u2 = leaky(ur[mb][nb][q] + brp);
                o4[q] = (bf16)((float)uv4[q] * u2);
            }
            *(bf16x4*)(updT + (size_t)col * C2 + o) = o4;
        }
}

// ---------------------------------------------------------------------------
// k_out: M=512, K=768 ([xT(512); updT(256)]), N=8192 -> out fp32 [b][o][v]
// ---------------------------------------------------------------------------
__global__ __launch_bounds__(128, 2) void k_out(
    const bf16* __restrict__ xT, const bf16* __restrict__ updT,
    const bf16* __restrict__ wf, const float* __restrict__ bfp,
    float* __restrict__ out)
{
    __shared__ __align__(16) bf16 L[2][2][64 * LDSW];
    const int t = threadIdx.x, lane = t & 63, wn = t >> 6;
    const int lr = lane & 15, kg = lane >> 4;
    const int n0 = blockIdx.x * 64, m0 = blockIdx.y * 64;
    const int srow = t >> 1, scolh = (t & 1) * 32;

    f32x4 acc[4][2];
    #pragma unroll
    for (int mb = 0; mb < 4; mb++)
        #pragma unroll
        for (int nb = 0; nb < 2; nb++) acc[mb][nb] = 0.f;

    Stage sA, sB;
    auto issueStep = [&](int s) {
        issue_rows(sA, wf, 768, m0 + srow, s * 64 + scolh);
        if (s < 8) issue_rows(sB, xT, C, n0 + srow, s * 64 + scolh);
        else       issue_rows(sB, updT, C2, n0 + srow, (s - 8) * 64 + scolh);
    };

    issueStep(0);
    commit(L[0][0], sA, t);
    commit(L[0][1], sB, t);
    int cb = 0;
    #pragma unroll 1
    for (int s = 0; s < 12; ++s) {
        __syncthreads();
        if (s + 1 < 12) issueStep(s + 1);
        mm64(L[cb][0], L[cb][1], acc, lr, kg, wn * 32);
        __syncthreads();
        if (s + 1 < 12) { commit(L[cb ^ 1][0], sA, t); commit(L[cb ^ 1][1], sB, t); }
        cb ^= 1;
    }

    f32x4 bfv[4];
    #pragma unroll
    for (int mb = 0; mb < 4; mb++)
        bfv[mb] = *(const f32x4*)(bfp + m0 + mb * 16 + kg * 4);
    #pragma unroll
    for (int mb = 0; mb < 4; mb++)
        #pragma unroll
        for (int nb = 0; nb < 2; nb++) {
            const int col = n0 + wn * 32 + nb * 16 + lr;
            const int b = col >> 12, v = col & 4095;
            const int o = m0 + mb * 16 + kg * 4;
            #pragma unroll
            for (int q = 0; q < 4; q++)
                out[(((size_t)b * C + o + q) << 12) + v] = leaky(acc[mb][nb][q] + bfv[mb][q]);
        }
}

// ---------------------------------------------------------------------------
extern "C" void kernel_launch(void* const* d_in, const int* in_sizes, int n_in,
                              void* d_out, int out_size, void* d_ws, size_t ws_size,
                              hipStream_t stream)
{
    const float* x    = (const float*)d_in[0];
    const float* topo = (const float*)d_in[1];
    const float* w_ea = (const float*)d_in[2];
    const float* b_ea = (const float*)d_in[3];
    const float* g_ea = (const float*)d_in[4];
    const float* be_ea= (const float*)d_in[5];
    const float* rm_ea= (const float*)d_in[6];
    const float* rv_ea= (const float*)d_in[7];
    const float* w_v  = (const float*)d_in[8];
    const float* b_v  = (const float*)d_in[9];
    const float* g_v  = (const float*)d_in[10];
    const float* be_v = (const float*)d_in[11];
    const float* rm_v = (const float*)d_in[12];
    const float* rv_v = (const float*)d_in[13];
    const float* w_e  = (const float*)d_in[14];
    const float* b_e  = (const float*)d_in[15];
    const float* g_e  = (const float*)d_in[16];
    const float* be_e = (const float*)d_in[17];
    const float* rm_e = (const float*)d_in[18];
    const float* rv_e = (const float*)d_in[19];
    const float* w_r  = (const float*)d_in[20];
    const float* b_r  = (const float*)d_in[21];
    const float* g_r  = (const float*)d_in[22];
    const float* be_r = (const float*)d_in[23];
    const float* rm_r = (const float*)d_in[24];
    const float* rv_r = (const float*)d_in[25];
    const float* w_f  = (const float*)d_in[26];
    const float* g_f  = (const float*)d_in[27];
    const float* be_f = (const float*)d_in[28];
    const float* rm_f = (const float*)d_in[29];
    const float* rv_f = (const float*)d_in[30];

    char* base = (char*)d_ws;
    size_t off = 0;
    auto take = [&](size_t bytes) { size_t r = off; off = (off + bytes + 255) & ~(size_t)255; return r; };
    float* P    = (float*)(base + take(64 * 4));
    float* bvp  = (float*)(base + take(256 * 4));
    float* bep  = (float*)(base + take(256 * 4));
    float* bfp  = (float*)(base + take(512 * 4));
    bf16*  wvp  = (bf16*)(base + take((size_t)262144 * 2));
    bf16*  wep  = (bf16*)(base + take((size_t)262144 * 2));
    bf16*  wfp  = (bf16*)(base + take((size_t)393216 * 2));
    bf16*  xT   = (bf16*)(base + take((size_t)NROWS * C * 2));
    bf16*  aggT = (bf16*)(base + take((size_t)NROWS * C * 2));
    bf16*  uvT  = (bf16*)(base + take((size_t)NROWS * C2 * 2));
    bf16*  updT = (bf16*)(base + take((size_t)NROWS * C2 * 2));

    k_prep<<<3584, 256, 0, stream>>>(
        w_v, w_e, w_f,
        w_ea, b_ea, g_ea, be_ea, rm_ea, rv_ea,
        b_v, g_v, be_v, rm_v, rv_v,
        b_e, g_e, be_e, rm_e, rv_e,
        w_r, b_r, g_r, be_r, rm_r, rv_r,
        g_f, be_f, rm_f, rv_f,
        P, bvp, bep, bfp, wvp, wep, wfp);

    k_aggT<<<dim3(64, 8, 2), 256, 0, stream>>>(x, topo, P, xT, aggT);

    k_uv <<<dim3(128, 4), 128, 0, stream>>>(xT, aggT, wvp, bvp, uvT);
    k_upd<<<dim3(128, 4), 128, 0, stream>>>(xT, wep, bep, P, topo, uvT, updT);
    k_out<<<dim3(128, 8), 128, 0, stream>>>(xT, updT, wfp, bfp, (float*)d_out);
}

// Round 4
// 101.405 us; speedup vs baseline: 2.3082x; 2.3082x over previous
//
#include <hip/hip_runtime.h>

#define BATCH 2
#define C 512
#define C2 256
#define V 4096          // 16*16*16
#define NROWS 8192      // BATCH*V
#define EPS 1e-5f
#define SLOPE 0.01f
#define LDSW 40         // LDS row stride bf16 (80B)

typedef __bf16 bf16;
typedef __bf16 bf16x8 __attribute__((ext_vector_type(8)));
typedef __bf16 bf16x4 __attribute__((ext_vector_type(4)));
typedef float  f32x4  __attribute__((ext_vector_type(4)));

__device__ __forceinline__ float leaky(float x) { return x >= 0.f ? x : SLOPE * x; }

__device__ __forceinline__ int nbr(int v, int k) {
    int h = v & 15, w = (v >> 4) & 15, d = v >> 8;
    switch (k) {
        case 0: return (v & 0x0FF) | (((d + 15) & 15) << 8);
        case 1: return (v & 0x0FF) | (((d + 1) & 15) << 8);
        case 2: return (v & 0xF0F) | (((w + 15) & 15) << 4);
        case 3: return (v & 0xF0F) | (((w + 1) & 15) << 4);
        case 4: return (v & 0xFF0) | ((h + 15) & 15);
        default: return (v & 0xFF0) | ((h + 1) & 15);
    }
}

__device__ __forceinline__ void st_lds(bf16* lds, uint4 v, int t) {
    *(uint4*)(lds + (t >> 2) * LDSW + (t & 3) * 8) = v;
}

// one BK=32 step for one wave: tile 64M x 32N -> 4+2 ds_read_b128, 8 MFMA
__device__ __forceinline__ void mm32(const bf16* A, const bf16* B,
                                     f32x4 (&acc)[4][2], int abase, int bbase,
                                     int lr, int kg)
{
    bf16x8 af[4], bv[2];
    #pragma unroll
    for (int mb = 0; mb < 4; mb++)
        af[mb] = *(const bf16x8*)(A + (abase + mb * 16 + lr) * LDSW + kg * 8);
    #pragma unroll
    for (int nb = 0; nb < 2; nb++)
        bv[nb] = *(const bf16x8*)(B + (bbase + nb * 16 + lr) * LDSW + kg * 8);
    #pragma unroll
    for (int mb = 0; mb < 4; mb++)
        #pragma unroll
        for (int nb = 0; nb < 2; nb++)
            acc[mb][nb] = __builtin_amdgcn_mfma_f32_16x16x32_bf16(af[mb], bv[nb], acc[mb][nb], 0, 0, 0);
}

// ---------------------------------------------------------------------------
// prep: fold BN into weights/biases. wmain = [[Wv1,Wv2],[We1,0]] (512x1024).
// ---------------------------------------------------------------------------
__global__ __launch_bounds__(256) void k_prep(
    const float* wv, const float* we, const float* wf,
    const float* w_ea, const float* b_ea, const float* g_ea, const float* be_ea,
    const float* rm_ea, const float* rv_ea,
    const float* b_v, const float* g_v, const float* be_v, const float* rm_v, const float* rv_v,
    const float* b_e, const float* g_e, const float* be_e, const float* rm_e, const float* rv_e,
    const float* w_r, const float* b_r, const float* g_r, const float* be_r,
    const float* rm_r, const float* rv_r,
    const float* g_f, const float* be_f, const float* rm_f, const float* rv_f,
    float* P, float* obv, float* obe, float* obf,
    bf16* wmain, bf16* we2, bf16* owf)
{
    int i = blockIdx.x * 256 + threadIdx.x;
    if (i < 524288) {                       // wmain 512x1024
        int o = i >> 10, c = i & 1023;
        float val;
        if (o < 256) val = rsqrtf(rv_v[o] + EPS) * g_v[o] * wv[(size_t)o * 1024 + c];
        else {
            int oe = o - 256;
            val = (c < 512) ? rsqrtf(rv_e[oe] + EPS) * g_e[oe] * we[(size_t)oe * 1024 + c] : 0.f;
        }
        wmain[i] = (bf16)val;
    } else if (i < 655360) {                // we2 256x512
        int j = i - 524288; int o = j >> 9, c = j & 511;
        we2[j] = (bf16)(rsqrtf(rv_e[o] + EPS) * g_e[o] * we[(size_t)o * 1024 + 512 + c]);
    } else if (i < 1048576) {               // wf 512x768
        int j = i - 655360; int o = j / 768;
        owf[j] = (bf16)(rsqrtf(rv_f[o] + EPS) * g_f[o] * wf[j]);
    }
    if (blockIdx.x == 0) {
        int t = threadIdx.x;
        obf[t]       = be_f[t]       - rsqrtf(rv_f[t]       + EPS) * g_f[t]       * rm_f[t];
        obf[t + 256] = be_f[t + 256] - rsqrtf(rv_f[t + 256] + EPS) * g_f[t + 256] * rm_f[t + 256];
        float sv = rsqrtf(rv_v[t] + EPS) * g_v[t];
        obv[t] = sv * (b_v[t] - rm_v[t]) + be_v[t];
        float se = rsqrtf(rv_e[t] + EPS) * g_e[t];
        obe[t] = se * (b_e[t] - rm_e[t]) + be_e[t];
        if (t < 6) {
            float sa = rsqrtf(rv_ea[0] + EPS) * g_ea[0];
            P[t] = sa * w_ea[t];
            float sr = rsqrtf(rv_r[0] + EPS) * g_r[0];
            P[8 + t] = sr * w_r[t];
        }
        if (t == 6) {
            float sa = rsqrtf(rv_ea[0] + EPS) * g_ea[0];
            P[6] = sa * (b_ea[0] - rm_ea[0]) + be_ea[0];
            float sr = rsqrtf(rv_r[0] + EPS) * g_r[0];
            P[14] = sr * (b_r[0] - rm_r[0]) + be_r[0];
        }
    }
}

// ---------------------------------------------------------------------------
// k_aggT: compute agg; write xT/aggT transposed [b*V+v][c] bf16 via LDS.
// ---------------------------------------------------------------------------
__global__ __launch_bounds__(256) void k_aggT(
    const float* __restrict__ x, const float* __restrict__ topo,
    const float* __restrict__ P,
    bf16* __restrict__ xT, bf16* __restrict__ aggT)
{
    __shared__ float T[64][65];
    const int t = threadIdx.x;
    const int b = blockIdx.z, ct = blockIdx.y * 64, vt = blockIdx.x * 64;
    const int cl = t >> 2;
    const int c  = ct + cl;
    const int vl0 = (t & 3) * 16;
    const int v0 = vt + vl0;
    const int w = (v0 >> 4) & 15, d = v0 >> 8;
    const float* xp = x + (((size_t)b * C + c) << 12);

    float xr[16], xd0[16], xd1[16], xw0[16], xw1[16];
    #pragma unroll
    for (int i = 0; i < 4; i++) {
        float4 a;
        a = ((const float4*)(xp + v0))[i];                        xr [4*i]=a.x; xr [4*i+1]=a.y; xr [4*i+2]=a.z; xr [4*i+3]=a.w;
        a = ((const float4*)(xp + (((d+15)&15)<<8) + (w<<4)))[i]; xd0[4*i]=a.x; xd0[4*i+1]=a.y; xd0[4*i+2]=a.z; xd0[4*i+3]=a.w;
        a = ((const float4*)(xp + (((d+ 1)&15)<<8) + (w<<4)))[i]; xd1[4*i]=a.x; xd1[4*i+1]=a.y; xd1[4*i+2]=a.z; xd1[4*i+3]=a.w;
        a = ((const float4*)(xp + (d<<8) + (((w+15)&15)<<4)))[i]; xw0[4*i]=a.x; xw0[4*i+1]=a.y; xw0[4*i+2]=a.z; xw0[4*i+3]=a.w;
        a = ((const float4*)(xp + (d<<8) + (((w+ 1)&15)<<4)))[i]; xw1[4*i]=a.x; xw1[4*i+1]=a.y; xw1[4*i+2]=a.z; xw1[4*i+3]=a.w;
    }

    #pragma unroll
    for (int p = 0; p < 2; ++p) {
        float val[16];
        if (p == 0) {
            #pragma unroll
            for (int j = 0; j < 16; j++) val[j] = xr[j];
        } else {
            #pragma unroll
            for (int j = 0; j < 16; j++) {
                const float* tp = topo + (size_t)(v0 + j) * 6;
                float s = P[6];
                s = fmaf(P[0], fmaf(xd0[j], xr[j], tp[0]), s);
                s = fmaf(P[1], fmaf(xd1[j], xr[j], tp[1]), s);
                s = fmaf(P[2], fmaf(xw0[j], xr[j], tp[2]), s);
                s = fmaf(P[3], fmaf(xw1[j], xr[j], tp[3]), s);
                s = fmaf(P[4], fmaf(xr[(j+15)&15], xr[j], tp[4]), s);
                s = fmaf(P[5], fmaf(xr[(j+ 1)&15], xr[j], tp[5]), s);
                val[j] = leaky(s);
            }
        }
        __syncthreads();
        #pragma unroll
        for (int j = 0; j < 16; j++) T[cl][vl0 + j] = val[j];
        __syncthreads();
        const int vr = t >> 2, c0 = (t & 3) * 16;
        bf16x8 lo, hi;
        #pragma unroll
        for (int i = 0; i < 8; i++) {
            lo[i] = (bf16)T[c0 + i][vr];
            hi[i] = (bf16)T[c0 + 8 + i][vr];
        }
        bf16* dst = (p == 0) ? xT : aggT;
        bf16* dp = dst + ((size_t)(b << 12) + vt + vr) * C + ct + c0;
        *(bf16x8*)dp = lo;
        *(bf16x8*)(dp + 8) = hi;
    }
}

// ---------------------------------------------------------------------------
// k_main: M=512 ([Wv;We1-pad]) x N=8192 x K=1024 ([xT;aggT]).
// rows 0-255 -> uvT = leaky(.+bv) bf16;  rows 256-511 -> sxe raw fp32.
// ---------------------------------------------------------------------------
__global__ __launch_bounds__(512, 4) void k_main(
    const bf16* __restrict__ xT, const bf16* __restrict__ aggT,
    const bf16* __restrict__ wm, const float* __restrict__ bvp,
    bf16* __restrict__ uvT, float* __restrict__ sxe)
{
    __shared__ __align__(16) bf16 L[2][2][128 * LDSW];
    const int t = threadIdx.x, lane = t & 63, wid = t >> 6;
    const int wmi = wid >> 2, wni = wid & 3;
    const int lr = lane & 15, kg = lane >> 4;
    const int n0 = blockIdx.x * 128, m0 = blockIdx.y * 128;
    const int srow = t >> 2, scol = (t & 3) * 8;

    f32x4 acc[4][2];
    #pragma unroll
    for (int mb = 0; mb < 4; mb++)
        #pragma unroll
        for (int nb = 0; nb < 2; nb++) acc[mb][nb] = 0.f;

    uint4 sA, sB;
    auto issue = [&](int s) {
        sA = *(const uint4*)(wm + (size_t)(m0 + srow) * 1024 + s * 32 + scol);
        const bf16* bs = (s < 16) ? xT : aggT;
        sB = *(const uint4*)(bs + (size_t)(n0 + srow) * C + (s & 15) * 32 + scol);
    };

    issue(0);
    st_lds(L[0][0], sA, t); st_lds(L[0][1], sB, t);
    issue(1);
    __syncthreads();
    #pragma unroll 1
    for (int s = 0; s < 32; ++s) {
        mm32(L[s & 1][0], L[s & 1][1], acc, wmi * 64, wni * 32, lr, kg);
        if (s + 1 < 32) {
            st_lds(L[(s + 1) & 1][0], sA, t); st_lds(L[(s + 1) & 1][1], sB, t);
            if (s + 2 < 32) issue(s + 2);
            __syncthreads();
        }
    }

    if (m0 < 256) {
        f32x4 bvv[4];
        #pragma unroll
        for (int mb = 0; mb < 4; mb++)
            bvv[mb] = *(const f32x4*)(bvp + m0 + wmi * 64 + mb * 16 + kg * 4);
        #pragma unroll
        for (int mb = 0; mb < 4; mb++)
            #pragma unroll
            for (int nb = 0; nb < 2; nb++) {
                const int col = n0 + wni * 32 + nb * 16 + lr;
                const int o = m0 + wmi * 64 + mb * 16 + kg * 4;
                bf16x4 o4;
                #pragma unroll
                for (int q = 0; q < 4; q++)
                    o4[q] = (bf16)leaky(acc[mb][nb][q] + bvv[mb][q]);
                *(bf16x4*)(uvT + (size_t)col * C2 + o) = o4;
            }
    } else {
        #pragma unroll
        for (int mb = 0; mb < 4; mb++)
            #pragma unroll
            for (int nb = 0; nb < 2; nb++) {
                const int col = n0 + wni * 32 + nb * 16 + lr;
                const int o = (m0 - 256) + wmi * 64 + mb * 16 + kg * 4;
                *(f32x4*)(sxe + (size_t)col * C2 + o) = acc[mb][nb];
            }
    }
}

// ---------------------------------------------------------------------------
// k_edge: one batched GEMM M=256 x N'=6*8192 x K=512.
// B built on the fly: e = xT[r]*xT[nbr_k(r)] + topo[v][k].  Output se raw bf16.
// ---------------------------------------------------------------------------
__global__ __launch_bounds__(512, 4) void k_edge(
    const bf16* __restrict__ xT, const bf16* __restrict__ we2,
    const float* __restrict__ topo, bf16* __restrict__ se)
{
    __shared__ __align__(16) bf16 L[2][2][128 * LDSW];
    const int t = threadIdx.x, lane = t & 63, wid = t >> 6;
    const int wmi = wid >> 2, wni = wid & 3;
    const int lr = lane & 15, kg = lane >> 4;
    const int n0 = blockIdx.x * 128, m0 = blockIdx.y * 128;
    const int kk = n0 >> 13;                 // edge index (tile never crosses)
    const int srow = t >> 2, scol = (t & 3) * 8;
    const int r = (n0 & 8191) + srow;        // (b,v) row this thread stages
    const int bb = r >> 12, vv = r & 4095;
    const int rn = (bb << 12) | nbr(vv, kk);
    const float tp = topo[vv * 6 + kk];

    f32x4 acc[4][2];
    #pragma unroll
    for (int mb = 0; mb < 4; mb++)
        #pragma unroll
        for (int nb = 0; nb < 2; nb++) acc[mb][nb] = 0.f;

    uint4 sA, sB, sBn;
    auto issue = [&](int s) {
        sA  = *(const uint4*)(we2 + (size_t)(m0 + srow) * 512 + s * 32 + scol);
        sB  = *(const uint4*)(xT + (size_t)r  * C + s * 32 + scol);
        sBn = *(const uint4*)(xT + (size_t)rn * C + s * 32 + scol);
    };
    auto commitB = [&](bf16* lds) {
        bf16x8 xa = *(const bf16x8*)&sB;
        bf16x8 xn = *(const bf16x8*)&sBn;
        bf16x8 e;
        #pragma unroll
        for (int i = 0; i < 8; i++)
            e[i] = (bf16)fmaf((float)xa[i], (float)xn[i], tp);
        *(bf16x8*)(lds + (t >> 2) * LDSW + (t & 3) * 8) = e;
    };

    issue(0);
    st_lds(L[0][0], sA, t); commitB(L[0][1]);
    issue(1);
    __syncthreads();
    #pragma unroll 1
    for (int s = 0; s < 16; ++s) {
        mm32(L[s & 1][0], L[s & 1][1], acc, wmi * 64, wni * 32, lr, kg);
        if (s + 1 < 16) {
            st_lds(L[(s + 1) & 1][0], sA, t); commitB(L[(s + 1) & 1][1]);
            if (s + 2 < 16) issue(s + 2);
            __syncthreads();
        }
    }

    #pragma unroll
    for (int mb = 0; mb < 4; mb++)
        #pragma unroll
        for (int nb = 0; nb < 2; nb++) {
            const int col = n0 + wni * 32 + nb * 16 + lr;
            const int rout = col & 8191;
            const int o = m0 + wmi * 64 + mb * 16 + kg * 4;
            bf16x4 o4;
            #pragma unroll
            for (int q = 0; q < 4; q++) o4[q] = (bf16)acc[mb][nb][q];
            *(bf16x4*)(se + ((size_t)kk * NROWS + rout) * C2 + o) = o4;
        }
}

// ---------------------------------------------------------------------------
// k_comb: ur = sum_k wr'_k * leaky(sxe + se_k + be'); updT = uvT * leaky(ur+br')
// ---------------------------------------------------------------------------
__global__ __launch_bounds__(256) void k_comb(
    const float* __restrict__ sxe, const bf16* __restrict__ se,
    const bf16* __restrict__ uvT, const float* __restrict__ bep,
    const float* __restrict__ P, bf16* __restrict__ updT)
{
    const int g = blockIdx.x * 256 + threadIdx.x;      // over NROWS*C2/8
    const int row = g >> 5, o0 = (g & 31) * 8;
    const size_t base = (size_t)row * C2 + o0;

    f32x4 sx0 = *(const f32x4*)(sxe + base);
    f32x4 sx1 = *(const f32x4*)(sxe + base + 4);
    f32x4 be0 = *(const f32x4*)(bep + o0);
    f32x4 be1 = *(const f32x4*)(bep + o0 + 4);
    float ur[8] = {};
    #pragma unroll
    for (int k = 0; k < 6; k++) {
        bf16x8 s8 = *(const bf16x8*)(se + (size_t)k * NROWS * C2 + base);
        const float wrk = P[8 + k];
        #pragma unroll
        for (int i = 0; i < 4; i++) {
            ur[i]     = fmaf(wrk, leaky(sx0[i] + (float)s8[i]     + be0[i]), ur[i]);
            ur[i + 4] = fmaf(wrk, leaky(sx1[i] + (float)s8[i + 4] + be1[i]), ur[i + 4]);
        }
    }
    const float brp = P[14];
    bf16x8 uv8 = *(const bf16x8*)(uvT + base);
    bf16x8 o8;
    #pragma unroll
    for (int i = 0; i < 8; i++)
        o8[i] = (bf16)((float)uv8[i] * leaky(ur[i] + brp));
    *(bf16x8*)(updT + base) = o8;
}

// ---------------------------------------------------------------------------
// k_out: M=512 x N=8192 x K=768 ([xT; updT]) -> d_out fp32 [b][o][v]
// ---------------------------------------------------------------------------
__global__ __launch_bounds__(512, 4) void k_out(
    const bf16* __restrict__ xT, const bf16* __restrict__ updT,
    const bf16* __restrict__ wf, const float* __restrict__ bfp,
    float* __restrict__ out)
{
    __shared__ __align__(16) bf16 L[2][2][128 * LDSW];
    const int t = threadIdx.x, lane = t & 63, wid = t >> 6;
    const int wmi = wid >> 2, wni = wid & 3;
    const int lr = lane & 15, kg = lane >> 4;
    const int n0 = blockIdx.x * 128, m0 = blockIdx.y * 128;
    const int srow = t >> 2, scol = (t & 3) * 8;

    f32x4 acc[4][2];
    #pragma unroll
    for (int mb = 0; mb < 4; mb++)
        #pragma unroll
        for (int nb = 0; nb < 2; nb++) acc[mb][nb] = 0.f;

    uint4 sA, sB;
    auto issue = [&](int s) {
        sA = *(const uint4*)(wf + (size_t)(m0 + srow) * 768 + s * 32 + scol);
        if (s < 16) sB = *(const uint4*)(xT   + (size_t)(n0 + srow) * C  + s * 32 + scol);
        else        sB = *(const uint4*)(updT + (size_t)(n0 + srow) * C2 + (s - 16) * 32 + scol);
    };

    issue(0);
    st_lds(L[0][0], sA, t); st_lds(L[0][1], sB, t);
    issue(1);
    __syncthreads();
    #pragma unroll 1
    for (int s = 0; s < 24; ++s) {
        mm32(L[s & 1][0], L[s & 1][1], acc, wmi * 64, wni * 32, lr, kg);
        if (s + 1 < 24) {
            st_lds(L[(s + 1) & 1][0], sA, t); st_lds(L[(s + 1) & 1][1], sB, t);
            if (s + 2 < 24) issue(s + 2);
            __syncthreads();
        }
    }

    f32x4 bfv[4];
    #pragma unroll
    for (int mb = 0; mb < 4; mb++)
        bfv[mb] = *(const f32x4*)(bfp + m0 + wmi * 64 + mb * 16 + kg * 4);
    #pragma unroll
    for (int mb = 0; mb < 4; mb++)
        #pragma unroll
        for (int nb = 0; nb < 2; nb++) {
            const int col = n0 + wni * 32 + nb * 16 + lr;
            const int b = col >> 12, v = col & 4095;
            const int o = m0 + wmi * 64 + mb * 16 + kg * 4;
            #pragma unroll
            for (int q = 0; q < 4; q++)
                out[(((size_t)b * C + o + q) << 12) + v] = leaky(acc[mb][nb][q] + bfv[mb][q]);
        }
}

// ---------------------------------------------------------------------------
extern "C" void kernel_launch(void* const* d_in, const int* in_sizes, int n_in,
                              void* d_out, int out_size, void* d_ws, size_t ws_size,
                              hipStream_t stream)
{
    const float* x    = (const float*)d_in[0];
    const float* topo = (const float*)d_in[1];
    const float* w_ea = (const float*)d_in[2];
    const float* b_ea = (const float*)d_in[3];
    const float* g_ea = (const float*)d_in[4];
    const float* be_ea= (const float*)d_in[5];
    const float* rm_ea= (const float*)d_in[6];
    const float* rv_ea= (const float*)d_in[7];
    const float* w_v  = (const float*)d_in[8];
    const float* b_v  = (const float*)d_in[9];
    const float* g_v  = (const float*)d_in[10];
    const float* be_v = (const float*)d_in[11];
    const float* rm_v = (const float*)d_in[12];
    const float* rv_v = (const float*)d_in[13];
    const float* w_e  = (const float*)d_in[14];
    const float* b_e  = (const float*)d_in[15];
    const float* g_e  = (const float*)d_in[16];
    const float* be_e = (const float*)d_in[17];
    const float* rm_e = (const float*)d_in[18];
    const float* rv_e = (const float*)d_in[19];
    const float* w_r  = (const float*)d_in[20];
    const float* b_r  = (const float*)d_in[21];
    const float* g_r  = (const float*)d_in[22];
    const float* be_r = (const float*)d_in[23];
    const float* rm_r = (const float*)d_in[24];
    const float* rv_r = (const float*)d_in[25];
    const float* w_f  = (const float*)d_in[26];
    const float* g_f  = (const float*)d_in[27];
    const float* be_f = (const float*)d_in[28];
    const float* rm_f = (const float*)d_in[29];
    const float* rv_f = (const float*)d_in[30];

    char* base = (char*)d_ws;
    size_t off = 0;
    auto take = [&](size_t bytes) { size_t r = off; off = (off + bytes + 255) & ~(size_t)255; return r; };
    float* P    = (float*)(base + take(64 * 4));
    float* bvp  = (float*)(base + take(256 * 4));
    float* bep  = (float*)(base + take(256 * 4));
    float* bfp  = (float*)(base + take(512 * 4));
    bf16*  wmp  = (bf16*)(base + take((size_t)524288 * 2));
    bf16*  we2p = (bf16*)(base + take((size_t)131072 * 2));
    bf16*  wfp  = (bf16*)(base + take((size_t)393216 * 2));
    bf16*  xT   = (bf16*)(base + take((size_t)NROWS * C * 2));
    bf16*  aggT = (bf16*)(base + take((size_t)NROWS * C * 2));
    bf16*  uvT  = (bf16*)(base + take((size_t)NROWS * C2 * 2));
    bf16*  updT = (bf16*)(base + take((size_t)NROWS * C2 * 2));
    float* sxe  = (float*)(base + take((size_t)NROWS * C2 * 4));
    bf16*  se   = (bf16*)(base + take((size_t)6 * NROWS * C2 * 2));

    k_prep<<<4096, 256, 0, stream>>>(
        w_v, w_e, w_f,
        w_ea, b_ea, g_ea, be_ea, rm_ea, rv_ea,
        b_v, g_v, be_v, rm_v, rv_v,
        b_e, g_e, be_e, rm_e, rv_e,
        w_r, b_r, g_r, be_r, rm_r, rv_r,
        g_f, be_f, rm_f, rv_f,
        P, bvp, bep, bfp, wmp, we2p, wfp);

    k_aggT<<<dim3(64, 8, 2), 256, 0, stream>>>(x, topo, P, xT, aggT);

    k_main<<<dim3(64, 4), 512, 0, stream>>>(xT, aggT, wmp, bvp, uvT, sxe);
    k_edge<<<dim3(384, 2), 512, 0, stream>>>(xT, we2p, topo, se);
    k_comb<<<dim3(NROWS * C2 / 8 / 256), 256, 0, stream>>>(sxe, se, uvT, bep, P, updT);
    k_out<<<dim3(64, 4), 512, 0, stream>>>(xT, updT, wfp, bfp, (float*)d_out);
}